// Round 16
// baseline (153.001 us; speedup 1.0000x reference)
//
#include <hip/hip_runtime.h>
#include <math.h>

#define B_    2
#define L_    2048
#define H_    16
#define D_    128
#define S_    40
#define NTOP_ 40
#define NCH_  8        // key chunks for attention
#define CHK_  256      // keys per chunk (attention)
#define VCH_  32       // L chunks for vmean
#define CAND_ 512      // refine candidate capacity

#define SCALE_ 0.08838834764831843f  // 1/sqrt(128)

typedef _Float16 half2_t __attribute__((ext_vector_type(2)));

__device__ __forceinline__ half2_t as_h2(unsigned int u) {
    union { unsigned int u; half2_t h; } x; x.u = u; return x.h;
}
__device__ __forceinline__ unsigned int h2pack(float a, float b) {  // RNE f16 pair
    union { half2_t h; unsigned int u; } x;
    x.h[0] = (_Float16)a; x.h[1] = (_Float16)b; return x.u;
}
#if __has_builtin(__builtin_amdgcn_fdot2)
__device__ __forceinline__ float FDOT2(half2_t a, half2_t b, float c) {
    return __builtin_amdgcn_fdot2(a, b, c, false);
}
#else
__device__ __forceinline__ float FDOT2(half2_t a, half2_t b, float c) {
    return c + (float)a[0] * (float)b[0] + (float)a[1] * (float)b[1];
}
#endif

// monotone float<->uint encoding (order-preserving, incl. negatives)
__device__ __forceinline__ unsigned int encf(float f) {
    unsigned int u = __float_as_uint(f);
    return (u & 0x80000000u) ? ~u : (u | 0x80000000u);
}
__device__ __forceinline__ float decf(unsigned int e) {
    unsigned int u = (e & 0x80000000u) ? (e ^ 0x80000000u) : ~e;
    return __uint_as_float(u);
}

// ---------------- kA: K->f16 pack + V partial sums (pure HBM job) ------------
__global__ __launch_bounds__(256) void kA_pack_vpart(const float* __restrict__ K,
                                                     const float* __restrict__ V,
                                                     unsigned int* __restrict__ Kf,
                                                     float* __restrict__ vpart,
                                                     int npack) {
    const int bid = blockIdx.x, t = threadIdx.x;
    if (bid < npack) {
        const int bh = bid >> 3, kc = bid & 7;
        const int h = bh & 15, b = bh >> 4;
        const float4* K4 = (const float4*)K;
        uint2* out2 = (uint2*)Kf;
        for (int j = 0; j < 32; ++j) {
            const int g = j * 256 + t;                 // 0..8191
            const int row = g >> 5, c = g & 31;
            const float4 v = K4[((size_t)(b * L_ + kc * 256 + row) * H_ + h) * 32 + c];
            out2[(size_t)(bh * L_ + kc * 256 + row) * 32 + c] =
                make_uint2(h2pack(v.x, v.y), h2pack(v.z, v.w));
        }
    } else {
        __shared__ float red[256];
        const int vbid = bid - npack;        // bh*VCH_ + lc
        const int bh  = vbid >> 5;
        const int lc  = vbid & (VCH_ - 1);
        const int h   = bh & 15, b = bh >> 4;
        const int d   = t & (D_ - 1);
        const int sub = t >> 7;
        float acc = 0.0f;
        const int l0 = lc * (L_ / VCH_);
        for (int l = l0 + sub; l < l0 + L_ / VCH_; l += 2)
            acc += V[((size_t)(b * L_ + l) * H_ + h) * D_ + d];
        red[t] = acc;
        __syncthreads();
        if (t < D_) vpart[(size_t)vbid * D_ + t] = red[t] + red[t + 128];
    }
}

// ---------------- k1: pure f16 sampled approx M (at the gather HW floor) -----
__global__ __launch_bounds__(256) void k1_sample_f16(const float* __restrict__ Q,
                                                     const uint4* __restrict__ KF,
                                                     const int* __restrict__ idx,
                                                     float* __restrict__ M) {
    const int sb   = blockIdx.x;
    const int xcd  = sb & 7;
    const int li   = sb >> 3;
    const int bh   = (xcd << 2) + (li >> 9);
    const int rb   = li & 511;
    const int t    = threadIdx.x;
    const int wave = t >> 6, lane = t & 63;
    const int q    = rb * 4 + wave;
    const int h    = bh & 15, b = bh >> 4;
    const int g    = lane >> 3, sub = lane & 7;

    const float4* Q4 = (const float4*)Q;
    const size_t rowQ = ((size_t)(b * L_ + q) * H_ + h) * 32;
    const int* ip = idx + q * S_;
    int kidx[5];
    #pragma unroll
    for (int s = 0; s < 5; ++s) kidx[s] = ip[s * 8 + g];

    const float4 qa0 = Q4[rowQ + 2 * sub];
    const float4 qa1 = Q4[rowQ + 2 * sub + 1];
    const float4 qb0 = Q4[rowQ + 16 + 2 * sub];
    const float4 qb1 = Q4[rowQ + 16 + 2 * sub + 1];

    uint4 kv[5][2];
    #pragma unroll
    for (int s = 0; s < 5; ++s) {
        const uint4* kr = KF + ((size_t)bh * L_ + kidx[s]) * 16;
        kv[s][0] = kr[sub];
        kv[s][1] = kr[8 + sub];
    }
    __builtin_amdgcn_sched_barrier(0);

    half2_t qh[8];
    qh[0][0] = (_Float16)qa0.x; qh[0][1] = (_Float16)qa0.y;
    qh[1][0] = (_Float16)qa0.z; qh[1][1] = (_Float16)qa0.w;
    qh[2][0] = (_Float16)qa1.x; qh[2][1] = (_Float16)qa1.y;
    qh[3][0] = (_Float16)qa1.z; qh[3][1] = (_Float16)qa1.w;
    qh[4][0] = (_Float16)qb0.x; qh[4][1] = (_Float16)qb0.y;
    qh[5][0] = (_Float16)qb0.z; qh[5][1] = (_Float16)qb0.w;
    qh[6][0] = (_Float16)qb1.x; qh[6][1] = (_Float16)qb1.y;
    qh[7][0] = (_Float16)qb1.z; qh[7][1] = (_Float16)qb1.w;

    float smax = -INFINITY, ssum = 0.0f;
    #pragma unroll
    for (int s = 0; s < 5; ++s) {
        float p = 0.f;
        p = FDOT2(qh[0], as_h2(kv[s][0].x), p);
        p = FDOT2(qh[1], as_h2(kv[s][0].y), p);
        p = FDOT2(qh[2], as_h2(kv[s][0].z), p);
        p = FDOT2(qh[3], as_h2(kv[s][0].w), p);
        p = FDOT2(qh[4], as_h2(kv[s][1].x), p);
        p = FDOT2(qh[5], as_h2(kv[s][1].y), p);
        p = FDOT2(qh[6], as_h2(kv[s][1].z), p);
        p = FDOT2(qh[7], as_h2(kv[s][1].w), p);
        p += __shfl_xor(p, 1);
        p += __shfl_xor(p, 2);
        p += __shfl_xor(p, 4);
        smax = fmaxf(smax, p);
        ssum += p;
    }
    #pragma unroll
    for (int o = 8; o < 64; o <<= 1) {
        smax = fmaxf(smax, __shfl_xor(smax, o));
        ssum += __shfl_xor(ssum, o);
    }
    if (lane == 0) M[(size_t)bh * L_ + q] = smax - ssum * (1.0f / L_);
}

// ---------------- k1 fallback (fp32 gather, no pack) -------------------------
__global__ __launch_bounds__(256) void k1_sample_f32(const float* __restrict__ Q,
                                                     const float* __restrict__ K,
                                                     const int* __restrict__ idx,
                                                     float* __restrict__ M) {
    const int sb   = blockIdx.x;
    const int xcd  = sb & 7;
    const int li   = sb >> 3;
    const int bh   = (xcd << 2) + (li >> 9);
    const int rb   = li & 511;
    const int t    = threadIdx.x;
    const int wave = t >> 6, lane = t & 63;
    const int q    = rb * 4 + wave;
    const int h    = bh & 15, b = bh >> 4;
    const int g    = lane >> 3, sub = lane & 7;

    const float4* Q4 = (const float4*)Q;
    const float4* K4 = (const float4*)K;
    const size_t rowQ = ((size_t)(b * L_ + q) * H_ + h) * 32;
    const size_t kbase = ((size_t)b * L_ * H_ + h) * 32 + sub;
    const int* ip = idx + q * S_;
    int kidx[5];
    #pragma unroll
    for (int s = 0; s < 5; ++s) kidx[s] = ip[s * 8 + g];
    const float4 qv0 = Q4[rowQ + 0 + sub];
    const float4 qv1 = Q4[rowQ + 8 + sub];
    const float4 qv2 = Q4[rowQ + 16 + sub];
    const float4 qv3 = Q4[rowQ + 24 + sub];
    float4 kv[5][4];
    #pragma unroll
    for (int s = 0; s < 5; ++s) {
        const float4* kb = K4 + kbase + (size_t)kidx[s] * (H_ * 32);
        kv[s][0] = kb[0]; kv[s][1] = kb[8]; kv[s][2] = kb[16]; kv[s][3] = kb[24];
    }
    __builtin_amdgcn_sched_barrier(0);
    float smax = -INFINITY, ssum = 0.0f;
    #pragma unroll
    for (int s = 0; s < 5; ++s) {
        float p = qv0.x * kv[s][0].x + qv0.y * kv[s][0].y + qv0.z * kv[s][0].z + qv0.w * kv[s][0].w
                + qv1.x * kv[s][1].x + qv1.y * kv[s][1].y + qv1.z * kv[s][1].z + qv1.w * kv[s][1].w
                + qv2.x * kv[s][2].x + qv2.y * kv[s][2].y + qv2.z * kv[s][2].z + qv2.w * kv[s][2].w
                + qv3.x * kv[s][3].x + qv3.y * kv[s][3].y + qv3.z * kv[s][3].z + qv3.w * kv[s][3].w;
        p += __shfl_xor(p, 1);
        p += __shfl_xor(p, 2);
        p += __shfl_xor(p, 4);
        smax = fmaxf(smax, p);
        ssum += p;
    }
    #pragma unroll
    for (int o = 8; o < 64; o <<= 1) {
        smax = fmaxf(smax, __shfl_xor(smax, o));
        ssum += __shfl_xor(ssum, o);
    }
    if (lane == 0) M[(size_t)bh * L_ + q] = smax - ssum * (1.0f / L_);
}

// ---------------- k2: radix-T40 + exact refine + select (+vmean fold) --------
__global__ __launch_bounds__(1024) void k2_rank_refine(const float* __restrict__ Mws,
                                                       const float* __restrict__ Q,
                                                       const float* __restrict__ K,
                                                       const int* __restrict__ idx,
                                                       const float* __restrict__ vpart,
                                                       float* __restrict__ vmean,
                                                       int* __restrict__ topk,
                                                       float delta) {
    const int bid = blockIdx.x, t = threadIdx.x;
    if (bid == 32) {
        for (int e = t; e < 32 * D_; e += 1024) {
            const int bh = e >> 7, d = e & 127;
            float s = 0.f;
            #pragma unroll
            for (int c = 0; c < VCH_; ++c)
                s += vpart[(size_t)(bh * VCH_ + c) * D_ + d];
            vmean[e] = s * (1.0f / L_);
        }
        return;
    }
    __shared__ unsigned int ue[L_];
    __shared__ int hist[256], sscan[256];
    __shared__ int sh_chosen, sh_need, sh_nc;
    __shared__ int clist[CAND_];
    __shared__ float cMx[CAND_];
    __shared__ unsigned int cmaxe[CAND_];
    __shared__ float csum[CAND_];
    const int bh = bid, h = bh & 15, b = bh >> 4;
    const float* Mrow = Mws + (size_t)bh * L_;
    for (int i = t; i < L_; i += 1024) ue[i] = encf(Mrow[i]);
    if (t == 0) sh_nc = 0;
    __syncthreads();

    unsigned int prefix = 0; int need = NTOP_;
    for (int l = 3; l >= 0; --l) {
        if (t < 256) hist[t] = 0;
        __syncthreads();
        for (int i = t; i < L_; i += 1024) {
            const unsigned int u = ue[i];
            const bool match = (l == 3) || ((u >> (8 * (l + 1))) == prefix);
            if (match) atomicAdd(&hist[(u >> (8 * l)) & 255], 1);
        }
        __syncthreads();
        if (t < 256) sscan[t] = hist[t];
        __syncthreads();
        for (int off = 1; off < 256; off <<= 1) {
            int v = 0;
            if (t < 256 && t + off < 256) v = sscan[t + off];
            __syncthreads();
            if (t < 256) sscan[t] += v;
            __syncthreads();
        }
        if (t < 256) {
            const int above = sscan[t] - hist[t];
            if (above < need && need <= above + hist[t]) { sh_chosen = t; sh_need = need - above; }
        }
        __syncthreads();
        prefix = (prefix << 8) | (unsigned int)sh_chosen;
        need = sh_need;
        __syncthreads();
    }
    const unsigned int ethr = encf(decf(prefix) - delta);
    for (int i = t; i < L_; i += 1024) {
        if (ue[i] >= ethr) {
            const int p = atomicAdd(&sh_nc, 1);
            if (p < CAND_) clist[p] = i;
        }
    }
    __syncthreads();
    const int nc = min(sh_nc, CAND_);
    for (int i = t; i < CAND_; i += 1024) { cmaxe[i] = 0x007FFFFFu; csum[i] = 0.f; }
    __syncthreads();

    const float4* Q4 = (const float4*)Q;
    const float4* K4 = (const float4*)K;
    const int grp = t >> 3, sub = t & 7;     // 128 groups
    for (int task = grp; task < nc * S_; task += 128) {
        const int ci = task / S_;
        const int s  = task - ci * S_;
        const int qq = clist[ci];
        const int ki = idx[qq * S_ + s];
        const float4* Kr = K4 + ((size_t)(b * L_ + ki) * H_ + h) * 32;
        const float4* Qr = Q4 + ((size_t)(b * L_ + qq) * H_ + h) * 32;
        float p = 0.f;
        #pragma unroll
        for (int qt2 = 0; qt2 < 4; ++qt2) {
            const float4 kv = Kr[qt2 * 8 + sub];
            const float4 qv = Qr[qt2 * 8 + sub];
            p += qv.x * kv.x + qv.y * kv.y + qv.z * kv.z + qv.w * kv.w;
        }
        p += __shfl_xor(p, 1);
        p += __shfl_xor(p, 2);
        p += __shfl_xor(p, 4);
        if (sub == 0) {
            atomicMax(&cmaxe[ci], encf(p));
            atomicAdd(&csum[ci], p);
        }
    }
    __syncthreads();
    if (t < nc) cMx[t] = decf(cmaxe[t]) - csum[t] * (1.0f / L_);
    __syncthreads();
    if (t < nc) {
        const float mi = cMx[t]; const int qi = clist[t];
        int rk = 0;
        for (int j = 0; j < nc; ++j) {
            const float mj = cMx[j];
            rk += (mj > mi) || (mj == mi && clist[j] < qi);
        }
        if (rk < NTOP_) topk[bh * NTOP_ + rk] = qi;
    }
}

// ---------------- k3: coalesced-K scores + softmax + PV + fill ---------------
// blocks 0..255 = (bh, kc), 1024 threads: all 40 u, one 256-key chunk.
// Score: wave w = (uq = w&3 owns 10 u, kr = w>>2 owns 64 keys); lane =
// (keysub = l>>4 of 4 keys, slice = l&15 of 8 dims). K loads are 512 B
// contiguous runs (16 lanes span a row) -> ~262K line requests total vs
// r14's 4.2M scattered 16 B segments (the hidden k1-style wall). Q rows in
// registers (2 passes x 5 u). Dot = 8 FMA + 4 shfl_xor within 16 lanes.
// PV: wave = (kr2 = w&1 key-half, ug = w>>1 owns 5 u); V coalesced; kr2=1
// partials combined via LDS. pout layout unchanged -> k_comb unchanged.
// blocks 256..383: sequential fill, 16384 float4 (256 KB) contiguous each.
__global__ __launch_bounds__(1024) void k3_scorepv_fill(const float* __restrict__ Q,
                                                        const float* __restrict__ K,
                                                        const float* __restrict__ V,
                                                        const int* __restrict__ topk,
                                                        const float* __restrict__ vmean,
                                                        float* __restrict__ pmax,
                                                        float* __restrict__ psum,
                                                        float* __restrict__ pout,
                                                        float* __restrict__ out) {
    __shared__ float S[40 * 260];           // 41.6 KB
    __shared__ float2 Ppv[40][64];          // 20.5 KB
    __shared__ float mrow[40];
    __shared__ int   tq[40];
    const int bid0 = blockIdx.x;
    const int t   = threadIdx.x;

    if (bid0 >= 256) {
        // ---- sequential fill: 16384 float4 per block ----
        const int fb = bid0 - 256;            // 0..127
        const float4* vm4 = (const float4*)vmean;
        float4* out4 = (float4*)out;
        const size_t base = (size_t)fb * 16384;
        #pragma unroll
        for (int k = 0; k < 16; ++k) {
            const size_t i = base + k * 1024 + t;
            const int d4 = (int)(i & 31);
            const int h  = (int)((i >> 5) & 15);
            const int b  = (int)(i >> 20);        // float4 per batch = 2^20
            out4[i] = vm4[((b << 4) + h) * 32 + d4];
        }
        return;
    }

    const int xcd = bid0 & 7;
    const int loc = bid0 >> 3;              // 0..31
    const int bh  = (xcd << 2) + (loc >> 3);
    const int kc  = loc & 7;
    const int h   = bh & 15, b = bh >> 4;
    const int w   = t >> 6, lane = t & 63;

    if (t < 40) tq[t] = topk[bh * NTOP_ + t];
    __syncthreads();

    // ---- scores ----
    {
        const int uq = w & 3, kr = w >> 2;
        const int keysub = lane >> 4, slice = lane & 15;
        const float4* Q4 = (const float4*)Q;
        const float4* K4 = (const float4*)K;
        #pragma unroll
        for (int half = 0; half < 2; ++half) {
            float4 qr0[5], qr1[5];
            #pragma unroll
            for (int u5 = 0; u5 < 5; ++u5) {
                const int u = uq * 10 + half * 5 + u5;
                const size_t qb = ((size_t)(b * L_ + tq[u]) * H_ + h) * 32 + slice * 2;
                qr0[u5] = Q4[qb];
                qr1[u5] = Q4[qb + 1];
            }
            for (int it = 0; it < 16; ++it) {
                const int key = kc * CHK_ + kr * 64 + it * 4 + keysub;
                const float4* Kr = K4 + ((size_t)(b * L_ + key) * H_ + h) * 32 + slice * 2;
                const float4 k0 = Kr[0];
                const float4 k1v = Kr[1];
                #pragma unroll
                for (int u5 = 0; u5 < 5; ++u5) {
                    float acc = qr0[u5].x * k0.x + qr0[u5].y * k0.y
                              + qr0[u5].z * k0.z + qr0[u5].w * k0.w
                              + qr1[u5].x * k1v.x + qr1[u5].y * k1v.y
                              + qr1[u5].z * k1v.z + qr1[u5].w * k1v.w;
                    acc += __shfl_xor(acc, 1);
                    acc += __shfl_xor(acc, 2);
                    acc += __shfl_xor(acc, 4);
                    acc += __shfl_xor(acc, 8);
                    if (slice == 0)
                        S[(uq * 10 + half * 5 + u5) * 260 + kr * 64 + it * 4 + keysub] =
                            acc * SCALE_;
                }
            }
        }
    }
    __syncthreads();

    // ---- per-u max (wave w handles u = w, w+16, w+32) ----
    {
        #pragma unroll
        for (int j = 0; j < 3; ++j) {
            const int u = w + 16 * j;
            if (u < NTOP_) {
                const float* Sr = S + u * 260;
                float v = fmaxf(fmaxf(Sr[lane], Sr[lane + 64]),
                                fmaxf(Sr[lane + 128], Sr[lane + 192]));
                #pragma unroll
                for (int o = 1; o < 64; o <<= 1) v = fmaxf(v, __shfl_xor(v, o, 64));
                if (lane == 0) mrow[u] = v;
            }
        }
    }
    __syncthreads();

    // ---- exponentiate ----
    for (int e = t; e < NTOP_ * 256; e += 1024) {
        const int u = e >> 8, k = e & 255;
        S[u * 260 + k] = __expf(S[u * 260 + k] - mrow[u]);
    }
    __syncthreads();

    // ---- per-u sum -> psum/pmax ----
    {
        #pragma unroll
        for (int j = 0; j < 3; ++j) {
            const int u = w + 16 * j;
            if (u < NTOP_) {
                const float* Sr = S + u * 260;
                float v = Sr[lane] + Sr[lane + 64] + Sr[lane + 128] + Sr[lane + 192];
                #pragma unroll
                for (int o = 1; o < 64; o <<= 1) v += __shfl_xor(v, o, 64);
                if (lane == 0) {
                    psum[(bh * NCH_ + kc) * NTOP_ + u] = v;
                    pmax[(bh * NCH_ + kc) * NTOP_ + u] = mrow[u];
                }
            }
        }
    }

    // ---- PV: wave = (kr2 = w&1, ug = w>>1 owns 5 u); lane = d-pair ----
    {
        const int kr2 = w & 1, ug = w >> 1;
        const int d2 = lane;
        float accA[5], accB[5];
        #pragma unroll
        for (int u5 = 0; u5 < 5; ++u5) { accA[u5] = 0.f; accB[u5] = 0.f; }
        const float2* Vb = (const float2*)(V +
            ((size_t)(b * L_ + kc * CHK_ + kr2 * 128) * H_ + h) * D_) + d2;
        for (int kq = 0; kq < 32; ++kq) {
            const float2 v0 = Vb[(size_t)(kq * 4 + 0) * (H_ * D_ / 2)];
            const float2 v1 = Vb[(size_t)(kq * 4 + 1) * (H_ * D_ / 2)];
            const float2 v2 = Vb[(size_t)(kq * 4 + 2) * (H_ * D_ / 2)];
            const float2 v3 = Vb[(size_t)(kq * 4 + 3) * (H_ * D_ / 2)];
            #pragma unroll
            for (int u5 = 0; u5 < 5; ++u5) {
                const float4 p = *(const float4*)&S[(ug * 5 + u5) * 260 + kr2 * 128 + kq * 4];
                accA[u5] += p.x * v0.x + p.y * v1.x + p.z * v2.x + p.w * v3.x;
                accB[u5] += p.x * v0.y + p.y * v1.y + p.z * v2.y + p.w * v3.y;
            }
        }
        if (kr2 == 1) {
            #pragma unroll
            for (int u5 = 0; u5 < 5; ++u5)
                Ppv[ug * 5 + u5][d2] = make_float2(accA[u5], accB[u5]);
        }
        __syncthreads();
        if (kr2 == 0) {
            #pragma unroll
            for (int u5 = 0; u5 < 5; ++u5) {
                const float2 o = Ppv[ug * 5 + u5][d2];
                float* pb = pout + (((size_t)(bh * NCH_ + kc)) * NTOP_ + ug * 5 + u5) * D_ + d2 * 2;
                *(float2*)pb = make_float2(accA[u5] + o.x, accB[u5] + o.y);
            }
        }
    }
}

// ---------------- k4: combine chunk partials, scatter to out -----------------
__global__ __launch_bounds__(128) void k_comb(const float* __restrict__ pmax,
                                              const float* __restrict__ psum,
                                              const float* __restrict__ pout,
                                              const int* __restrict__ topk,
                                              float* __restrict__ out) {
    const int bid = blockIdx.x;          // bh*40 + u
    const int bh  = bid / NTOP_;
    const int u   = bid - bh * NTOP_;
    const int h   = bh & 15, b = bh >> 4;
    const int t   = threadIdx.x;

    float pm[NCH_];
    float M = -INFINITY;
    #pragma unroll
    for (int c = 0; c < NCH_; ++c) {
        pm[c] = pmax[(bh * NCH_ + c) * NTOP_ + u];
        M = fmaxf(M, pm[c]);
    }
    float ssum = 0.0f, o = 0.0f;
    #pragma unroll
    for (int c = 0; c < NCH_; ++c) {
        const float w = __expf(pm[c] - M);
        ssum += psum[(bh * NCH_ + c) * NTOP_ + u] * w;
        o += pout[((size_t)(bh * NCH_ + c) * NTOP_ + u) * D_ + t] * w;
    }
    const int qi = topk[bh * NTOP_ + u];
    out[((size_t)(b * L_ + qi) * H_ + h) * D_ + t] = o / ssum;
}

extern "C" void kernel_launch(void* const* d_in, const int* in_sizes, int n_in,
                              void* d_out, int out_size, void* d_ws, size_t ws_size,
                              hipStream_t stream) {
    const float* Q  = (const float*)d_in[0];
    const float* K  = (const float*)d_in[1];
    const float* V  = (const float*)d_in[2];
    const int* idx  = (const int*)d_in[3];
    float* out      = (float*)d_out;

    char* ws = (char*)d_ws;
    size_t off = 0;
    float* Mws   = (float*)(ws + off); off += (size_t)65536 * 4;
    float* vpart = (float*)(ws + off); off += (size_t)1024 * 128 * 4;
    float* vmean = (float*)(ws + off); off += (size_t)4096 * 4;
    int*   topk  = (int*)(ws + off);   off += 1280 * 4;
    float* pmax  = (float*)(ws + off); off += (size_t)256 * 40 * 4;
    float* psum  = (float*)(ws + off); off += (size_t)256 * 40 * 4;
    float* pout  = (float*)(ws + off); off += (size_t)256 * 40 * 128 * 4;
    unsigned int* Kf = (unsigned int*)(ws + off);
    const size_t kf_bytes = (size_t)32 * L_ * D_ * 2;      // 16.8 MB
    const bool use_f16 = (ws_size >= off + kf_bytes);

    if (use_f16) {
        hipLaunchKernelGGL(kA_pack_vpart, dim3(256 + 1024), dim3(256), 0, stream,
                           K, V, Kf, vpart, 256);
        hipLaunchKernelGGL(k1_sample_f16, dim3(16384), dim3(256), 0, stream,
                           Q, (const uint4*)Kf, idx, Mws);
    } else {
        hipLaunchKernelGGL(kA_pack_vpart, dim3(1024), dim3(256), 0, stream,
                           K, V, Kf, vpart, 0);
        hipLaunchKernelGGL(k1_sample_f32, dim3(16384), dim3(256), 0, stream,
                           Q, K, idx, Mws);
    }
    hipLaunchKernelGGL(k2_rank_refine, dim3(33), dim3(1024), 0, stream,
                       Mws, Q, K, idx, vpart, vmean, topk, use_f16 ? 0.5f : 0.01f);
    hipLaunchKernelGGL(k3_scorepv_fill, dim3(384), dim3(1024), 0, stream,
                       Q, K, V, topk, vmean, pmax, psum, pout, out);
    hipLaunchKernelGGL(k_comb, dim3(1280), dim3(128), 0, stream,
                       pmax, psum, pout, topk, out);
}

// Round 17
// 127.930 us; speedup vs baseline: 1.1960x; 1.1960x over previous
//
#include <hip/hip_runtime.h>
#include <math.h>

#define B_    2
#define L_    2048
#define H_    16
#define D_    128
#define S_    40
#define NTOP_ 40
#define NCH_  8        // key chunks for attention
#define CHK_  256      // keys per chunk (attention)
#define VCH_  32       // L chunks for vmean
#define CAND_ 512      // refine candidate capacity

#define SCALE_ 0.08838834764831843f  // 1/sqrt(128)

typedef _Float16 half2_t __attribute__((ext_vector_type(2)));

__device__ __forceinline__ half2_t as_h2(unsigned int u) {
    union { unsigned int u; half2_t h; } x; x.u = u; return x.h;
}
__device__ __forceinline__ unsigned int h2pack(float a, float b) {  // RNE f16 pair
    union { half2_t h; unsigned int u; } x;
    x.h[0] = (_Float16)a; x.h[1] = (_Float16)b; return x.u;
}
#if __has_builtin(__builtin_amdgcn_fdot2)
__device__ __forceinline__ float FDOT2(half2_t a, half2_t b, float c) {
    return __builtin_amdgcn_fdot2(a, b, c, false);
}
#else
__device__ __forceinline__ float FDOT2(half2_t a, half2_t b, float c) {
    return c + (float)a[0] * (float)b[0] + (float)a[1] * (float)b[1];
}
#endif

// monotone float<->uint encoding (order-preserving, incl. negatives)
__device__ __forceinline__ unsigned int encf(float f) {
    unsigned int u = __float_as_uint(f);
    return (u & 0x80000000u) ? ~u : (u | 0x80000000u);
}
__device__ __forceinline__ float decf(unsigned int e) {
    unsigned int u = (e & 0x80000000u) ? (e ^ 0x80000000u) : ~e;
    return __uint_as_float(u);
}

// ---------------- kA: K->f16 pack + V partial sums (pure HBM job) ------------
__global__ __launch_bounds__(256) void kA_pack_vpart(const float* __restrict__ K,
                                                     const float* __restrict__ V,
                                                     unsigned int* __restrict__ Kf,
                                                     float* __restrict__ vpart,
                                                     int npack) {
    const int bid = blockIdx.x, t = threadIdx.x;
    if (bid < npack) {
        const int bh = bid >> 3, kc = bid & 7;
        const int h = bh & 15, b = bh >> 4;
        const float4* K4 = (const float4*)K;
        uint2* out2 = (uint2*)Kf;
        for (int j = 0; j < 32; ++j) {
            const int g = j * 256 + t;                 // 0..8191
            const int row = g >> 5, c = g & 31;
            const float4 v = K4[((size_t)(b * L_ + kc * 256 + row) * H_ + h) * 32 + c];
            out2[(size_t)(bh * L_ + kc * 256 + row) * 32 + c] =
                make_uint2(h2pack(v.x, v.y), h2pack(v.z, v.w));
        }
    } else {
        __shared__ float red[256];
        const int vbid = bid - npack;        // bh*VCH_ + lc
        const int bh  = vbid >> 5;
        const int lc  = vbid & (VCH_ - 1);
        const int h   = bh & 15, b = bh >> 4;
        const int d   = t & (D_ - 1);
        const int sub = t >> 7;
        float acc = 0.0f;
        const int l0 = lc * (L_ / VCH_);
        for (int l = l0 + sub; l < l0 + L_ / VCH_; l += 2)
            acc += V[((size_t)(b * L_ + l) * H_ + h) * D_ + d];
        red[t] = acc;
        __syncthreads();
        if (t < D_) vpart[(size_t)vbid * D_ + t] = red[t] + red[t + 128];
    }
}

// ---------------- k1: pure f16 sampled approx M (at the gather HW floor) -----
__global__ __launch_bounds__(256) void k1_sample_f16(const float* __restrict__ Q,
                                                     const uint4* __restrict__ KF,
                                                     const int* __restrict__ idx,
                                                     float* __restrict__ M) {
    const int sb   = blockIdx.x;
    const int xcd  = sb & 7;
    const int li   = sb >> 3;
    const int bh   = (xcd << 2) + (li >> 9);
    const int rb   = li & 511;
    const int t    = threadIdx.x;
    const int wave = t >> 6, lane = t & 63;
    const int q    = rb * 4 + wave;
    const int h    = bh & 15, b = bh >> 4;
    const int g    = lane >> 3, sub = lane & 7;

    const float4* Q4 = (const float4*)Q;
    const size_t rowQ = ((size_t)(b * L_ + q) * H_ + h) * 32;
    const int* ip = idx + q * S_;
    int kidx[5];
    #pragma unroll
    for (int s = 0; s < 5; ++s) kidx[s] = ip[s * 8 + g];

    const float4 qa0 = Q4[rowQ + 2 * sub];
    const float4 qa1 = Q4[rowQ + 2 * sub + 1];
    const float4 qb0 = Q4[rowQ + 16 + 2 * sub];
    const float4 qb1 = Q4[rowQ + 16 + 2 * sub + 1];

    uint4 kv[5][2];
    #pragma unroll
    for (int s = 0; s < 5; ++s) {
        const uint4* kr = KF + ((size_t)bh * L_ + kidx[s]) * 16;
        kv[s][0] = kr[sub];
        kv[s][1] = kr[8 + sub];
    }
    __builtin_amdgcn_sched_barrier(0);

    half2_t qh[8];
    qh[0][0] = (_Float16)qa0.x; qh[0][1] = (_Float16)qa0.y;
    qh[1][0] = (_Float16)qa0.z; qh[1][1] = (_Float16)qa0.w;
    qh[2][0] = (_Float16)qa1.x; qh[2][1] = (_Float16)qa1.y;
    qh[3][0] = (_Float16)qa1.z; qh[3][1] = (_Float16)qa1.w;
    qh[4][0] = (_Float16)qb0.x; qh[4][1] = (_Float16)qb0.y;
    qh[5][0] = (_Float16)qb0.z; qh[5][1] = (_Float16)qb0.w;
    qh[6][0] = (_Float16)qb1.x; qh[6][1] = (_Float16)qb1.y;
    qh[7][0] = (_Float16)qb1.z; qh[7][1] = (_Float16)qb1.w;

    float smax = -INFINITY, ssum = 0.0f;
    #pragma unroll
    for (int s = 0; s < 5; ++s) {
        float p = 0.f;
        p = FDOT2(qh[0], as_h2(kv[s][0].x), p);
        p = FDOT2(qh[1], as_h2(kv[s][0].y), p);
        p = FDOT2(qh[2], as_h2(kv[s][0].z), p);
        p = FDOT2(qh[3], as_h2(kv[s][0].w), p);
        p = FDOT2(qh[4], as_h2(kv[s][1].x), p);
        p = FDOT2(qh[5], as_h2(kv[s][1].y), p);
        p = FDOT2(qh[6], as_h2(kv[s][1].z), p);
        p = FDOT2(qh[7], as_h2(kv[s][1].w), p);
        p += __shfl_xor(p, 1);
        p += __shfl_xor(p, 2);
        p += __shfl_xor(p, 4);
        smax = fmaxf(smax, p);
        ssum += p;
    }
    #pragma unroll
    for (int o = 8; o < 64; o <<= 1) {
        smax = fmaxf(smax, __shfl_xor(smax, o));
        ssum += __shfl_xor(ssum, o);
    }
    if (lane == 0) M[(size_t)bh * L_ + q] = smax - ssum * (1.0f / L_);
}

// ---------------- k1 fallback (fp32 gather, no pack) -------------------------
__global__ __launch_bounds__(256) void k1_sample_f32(const float* __restrict__ Q,
                                                     const float* __restrict__ K,
                                                     const int* __restrict__ idx,
                                                     float* __restrict__ M) {
    const int sb   = blockIdx.x;
    const int xcd  = sb & 7;
    const int li   = sb >> 3;
    const int bh   = (xcd << 2) + (li >> 9);
    const int rb   = li & 511;
    const int t    = threadIdx.x;
    const int wave = t >> 6, lane = t & 63;
    const int q    = rb * 4 + wave;
    const int h    = bh & 15, b = bh >> 4;
    const int g    = lane >> 3, sub = lane & 7;

    const float4* Q4 = (const float4*)Q;
    const float4* K4 = (const float4*)K;
    const size_t rowQ = ((size_t)(b * L_ + q) * H_ + h) * 32;
    const size_t kbase = ((size_t)b * L_ * H_ + h) * 32 + sub;
    const int* ip = idx + q * S_;
    int kidx[5];
    #pragma unroll
    for (int s = 0; s < 5; ++s) kidx[s] = ip[s * 8 + g];
    const float4 qv0 = Q4[rowQ + 0 + sub];
    const float4 qv1 = Q4[rowQ + 8 + sub];
    const float4 qv2 = Q4[rowQ + 16 + sub];
    const float4 qv3 = Q4[rowQ + 24 + sub];
    float4 kv[5][4];
    #pragma unroll
    for (int s = 0; s < 5; ++s) {
        const float4* kb = K4 + kbase + (size_t)kidx[s] * (H_ * 32);
        kv[s][0] = kb[0]; kv[s][1] = kb[8]; kv[s][2] = kb[16]; kv[s][3] = kb[24];
    }
    __builtin_amdgcn_sched_barrier(0);
    float smax = -INFINITY, ssum = 0.0f;
    #pragma unroll
    for (int s = 0; s < 5; ++s) {
        float p = qv0.x * kv[s][0].x + qv0.y * kv[s][0].y + qv0.z * kv[s][0].z + qv0.w * kv[s][0].w
                + qv1.x * kv[s][1].x + qv1.y * kv[s][1].y + qv1.z * kv[s][1].z + qv1.w * kv[s][1].w
                + qv2.x * kv[s][2].x + qv2.y * kv[s][2].y + qv2.z * kv[s][2].z + qv2.w * kv[s][2].w
                + qv3.x * kv[s][3].x + qv3.y * kv[s][3].y + qv3.z * kv[s][3].z + qv3.w * kv[s][3].w;
        p += __shfl_xor(p, 1);
        p += __shfl_xor(p, 2);
        p += __shfl_xor(p, 4);
        smax = fmaxf(smax, p);
        ssum += p;
    }
    #pragma unroll
    for (int o = 8; o < 64; o <<= 1) {
        smax = fmaxf(smax, __shfl_xor(smax, o));
        ssum += __shfl_xor(ssum, o);
    }
    if (lane == 0) M[(size_t)bh * L_ + q] = smax - ssum * (1.0f / L_);
}

// ---------------- k2: radix-T40 + exact refine + select (+vmean fold) --------
__global__ __launch_bounds__(1024) void k2_rank_refine(const float* __restrict__ Mws,
                                                       const float* __restrict__ Q,
                                                       const float* __restrict__ K,
                                                       const int* __restrict__ idx,
                                                       const float* __restrict__ vpart,
                                                       float* __restrict__ vmean,
                                                       int* __restrict__ topk,
                                                       float delta) {
    const int bid = blockIdx.x, t = threadIdx.x;
    if (bid == 32) {
        for (int e = t; e < 32 * D_; e += 1024) {
            const int bh = e >> 7, d = e & 127;
            float s = 0.f;
            #pragma unroll
            for (int c = 0; c < VCH_; ++c)
                s += vpart[(size_t)(bh * VCH_ + c) * D_ + d];
            vmean[e] = s * (1.0f / L_);
        }
        return;
    }
    __shared__ unsigned int ue[L_];
    __shared__ int hist[256], sscan[256];
    __shared__ int sh_chosen, sh_need, sh_nc;
    __shared__ int clist[CAND_];
    __shared__ float cMx[CAND_];
    __shared__ unsigned int cmaxe[CAND_];
    __shared__ float csum[CAND_];
    const int bh = bid, h = bh & 15, b = bh >> 4;
    const float* Mrow = Mws + (size_t)bh * L_;
    for (int i = t; i < L_; i += 1024) ue[i] = encf(Mrow[i]);
    if (t == 0) sh_nc = 0;
    __syncthreads();

    unsigned int prefix = 0; int need = NTOP_;
    for (int l = 3; l >= 0; --l) {
        if (t < 256) hist[t] = 0;
        __syncthreads();
        for (int i = t; i < L_; i += 1024) {
            const unsigned int u = ue[i];
            const bool match = (l == 3) || ((u >> (8 * (l + 1))) == prefix);
            if (match) atomicAdd(&hist[(u >> (8 * l)) & 255], 1);
        }
        __syncthreads();
        if (t < 256) sscan[t] = hist[t];
        __syncthreads();
        for (int off = 1; off < 256; off <<= 1) {
            int v = 0;
            if (t < 256 && t + off < 256) v = sscan[t + off];
            __syncthreads();
            if (t < 256) sscan[t] += v;
            __syncthreads();
        }
        if (t < 256) {
            const int above = sscan[t] - hist[t];
            if (above < need && need <= above + hist[t]) { sh_chosen = t; sh_need = need - above; }
        }
        __syncthreads();
        prefix = (prefix << 8) | (unsigned int)sh_chosen;
        need = sh_need;
        __syncthreads();
    }
    const unsigned int ethr = encf(decf(prefix) - delta);
    for (int i = t; i < L_; i += 1024) {
        if (ue[i] >= ethr) {
            const int p = atomicAdd(&sh_nc, 1);
            if (p < CAND_) clist[p] = i;
        }
    }
    __syncthreads();
    const int nc = min(sh_nc, CAND_);
    for (int i = t; i < CAND_; i += 1024) { cmaxe[i] = 0x007FFFFFu; csum[i] = 0.f; }
    __syncthreads();

    const float4* Q4 = (const float4*)Q;
    const float4* K4 = (const float4*)K;
    const int grp = t >> 3, sub = t & 7;     // 128 groups
    for (int task = grp; task < nc * S_; task += 128) {
        const int ci = task / S_;
        const int s  = task - ci * S_;
        const int qq = clist[ci];
        const int ki = idx[qq * S_ + s];
        const float4* Kr = K4 + ((size_t)(b * L_ + ki) * H_ + h) * 32;
        const float4* Qr = Q4 + ((size_t)(b * L_ + qq) * H_ + h) * 32;
        float p = 0.f;
        #pragma unroll
        for (int qt2 = 0; qt2 < 4; ++qt2) {
            const float4 kv = Kr[qt2 * 8 + sub];
            const float4 qv = Qr[qt2 * 8 + sub];
            p += qv.x * kv.x + qv.y * kv.y + qv.z * kv.z + qv.w * kv.w;
        }
        p += __shfl_xor(p, 1);
        p += __shfl_xor(p, 2);
        p += __shfl_xor(p, 4);
        if (sub == 0) {
            atomicMax(&cmaxe[ci], encf(p));
            atomicAdd(&csum[ci], p);
        }
    }
    __syncthreads();
    if (t < nc) cMx[t] = decf(cmaxe[t]) - csum[t] * (1.0f / L_);
    __syncthreads();
    if (t < nc) {
        const float mi = cMx[t]; const int qi = clist[t];
        int rk = 0;
        for (int j = 0; j < nc; ++j) {
            const float mj = cMx[j];
            rk += (mj > mi) || (mj == mi && clist[j] < qi);
        }
        if (rk < NTOP_) topk[bh * NTOP_ + rk] = qi;
    }
}

// ---------------- k3: 512-thread score/PV (16 waves/CU) + sequential fill ----
// blocks 0..511 = (bh, kc8, uh2), 512 threads (8 waves): same per-block tile
// as r10 (20 u x 256 keys) and IDENTICAL memory redundancy (K x8, V x8,
// LDS-read counts), but 2x the waves -> occupancy 21% -> ~45% to hide the
// scattered-K-segment latency that pinned r14 at 50 us.
// Score: thread = (kq2 = t>>2 owns keys 2kq2..+1, ug = t&3 owns 5 u), acc[2][5].
// PV: wave = (kr2 = w&1 key-half, ug2 = w>>1 owns 5 u); halves combined in LDS.
// blocks 512..1023: sequential fill, 4096 float4 (16 KB) contiguous each.
__global__ __launch_bounds__(512) void k3_scorepv_fill(const float* __restrict__ Q,
                                                       const float* __restrict__ K,
                                                       const float* __restrict__ V,
                                                       const int* __restrict__ topk,
                                                       const float* __restrict__ vmean,
                                                       float* __restrict__ pmax,
                                                       float* __restrict__ psum,
                                                       float* __restrict__ pout,
                                                       float* __restrict__ out) {
    __shared__ float Qs[20 * 132];          // 10.6 KB
    __shared__ float S[20 * 260];           // 20.8 KB
    __shared__ float2 Ppv[20][64];          // 10.2 KB
    __shared__ float mrow[20];
    __shared__ int   tq[20];
    const int bid0 = blockIdx.x;
    const int t   = threadIdx.x;

    if (bid0 >= 512) {
        // ---- sequential fill: 4096 float4 per block ----
        const int fb = bid0 - 512;            // 0..511
        const float4* vm4 = (const float4*)vmean;
        float4* out4 = (float4*)out;
        const size_t base = (size_t)fb * 4096;
        #pragma unroll
        for (int k = 0; k < 8; ++k) {
            const size_t i = base + k * 512 + t;
            const int d4 = (int)(i & 31);
            const int h  = (int)((i >> 5) & 15);
            const int b  = (int)(i >> 20);        // float4 per batch = 2^20
            out4[i] = vm4[((b << 4) + h) * 32 + d4];
        }
        return;
    }

    const int xcd = bid0 & 7;
    const int loc = bid0 >> 3;              // 0..63
    const int bh  = (xcd << 2) + (loc >> 4);
    const int sub16 = loc & 15;
    const int kc  = sub16 >> 1;
    const int uh  = sub16 & 1;
    const int h   = bh & 15, b = bh >> 4;
    const int w   = t >> 6, lane = t & 63;

    if (t < 20) tq[t] = topk[bh * NTOP_ + uh * 20 + t];
    __syncthreads();

    // stage 20 Q rows (640 float4) over 512 threads
    {
        const float4* Q4 = (const float4*)Q;
        #pragma unroll
        for (int it = 0; it < 2; ++it) {
            const int i = it * 512 + t;
            if (i < 640) {
                const int u = i >> 5, dc = i & 31;
                *(float4*)&Qs[u * 132 + dc * 4] =
                    Q4[((size_t)(b * L_ + tq[u]) * H_ + h) * 32 + dc];
            }
        }
    }
    __syncthreads();

    // scores: thread = (kq2 = t>>2 owns keys 2kq2..+1, ug = t&3 owns 5 u)
    {
        const int kq2 = t >> 2, ug = t & 3;
        float acc[2][5];
        #pragma unroll
        for (int j = 0; j < 2; ++j)
            #pragma unroll
            for (int uu = 0; uu < 5; ++uu) acc[j][uu] = 0.f;
        const float4* Kb = (const float4*)K +
            ((size_t)(b * L_ + kc * CHK_ + kq2 * 2) * H_ + h) * 32;
        for (int dc = 0; dc < 32; ++dc) {
            float4 qv[5];
            #pragma unroll
            for (int uu = 0; uu < 5; ++uu)
                qv[uu] = *(const float4*)&Qs[(ug * 5 + uu) * 132 + dc * 4];
            #pragma unroll
            for (int j = 0; j < 2; ++j) {
                const float4 kv = Kb[(size_t)j * (H_ * 32) + dc];
                #pragma unroll
                for (int uu = 0; uu < 5; ++uu)
                    acc[j][uu] += qv[uu].x * kv.x + qv[uu].y * kv.y
                                + qv[uu].z * kv.z + qv[uu].w * kv.w;
            }
        }
        #pragma unroll
        for (int j = 0; j < 2; ++j)
            #pragma unroll
            for (int uu = 0; uu < 5; ++uu)
                S[(ug * 5 + uu) * 260 + kq2 * 2 + j] = acc[j][uu] * SCALE_;
    }
    __syncthreads();

    // per-u max: 8 waves, u = w + 8*jj (guard < 20)
    {
        #pragma unroll
        for (int jj = 0; jj < 3; ++jj) {
            const int u = w + 8 * jj;
            if (u < 20) {
                const float* Sr = S + u * 260;
                float v = fmaxf(fmaxf(Sr[lane], Sr[lane + 64]),
                                fmaxf(Sr[lane + 128], Sr[lane + 192]));
                #pragma unroll
                for (int o = 1; o < 64; o <<= 1) v = fmaxf(v, __shfl_xor(v, o, 64));
                if (lane == 0) mrow[u] = v;
            }
        }
    }
    __syncthreads();

    // exponentiate (20 x 256 entries over 512 threads)
    for (int e = t; e < 20 * 256; e += 512) {
        const int u = e >> 8, k = e & 255;
        S[u * 260 + k] = __expf(S[u * 260 + k] - mrow[u]);
    }
    __syncthreads();

    // per-u sum -> psum/pmax
    {
        #pragma unroll
        for (int jj = 0; jj < 3; ++jj) {
            const int u = w + 8 * jj;
            if (u < 20) {
                const float* Sr = S + u * 260;
                float v = Sr[lane] + Sr[lane + 64] + Sr[lane + 128] + Sr[lane + 192];
                #pragma unroll
                for (int o = 1; o < 64; o <<= 1) v += __shfl_xor(v, o, 64);
                if (lane == 0) {
                    psum[(bh * NCH_ + kc) * NTOP_ + uh * 20 + u] = v;
                    pmax[(bh * NCH_ + kc) * NTOP_ + uh * 20 + u] = mrow[u];
                }
            }
        }
    }

    // PV: wave = (kr2 = w&1 key-half, ug2 = w>>1 owns 5 u); lane d2 = dim pair
    {
        const int kr2 = w & 1, ug2 = w >> 1;
        const int d2 = lane;
        float accA[5], accB[5];
        #pragma unroll
        for (int uu = 0; uu < 5; ++uu) { accA[uu] = 0.f; accB[uu] = 0.f; }
        const float2* Vb = (const float2*)(V +
            ((size_t)(b * L_ + kc * CHK_ + kr2 * 128) * H_ + h) * D_) + d2;
        for (int kq = 0; kq < 32; ++kq) {
            const float2 v0 = Vb[(size_t)(kq * 4 + 0) * (H_ * D_ / 2)];
            const float2 v1 = Vb[(size_t)(kq * 4 + 1) * (H_ * D_ / 2)];
            const float2 v2 = Vb[(size_t)(kq * 4 + 2) * (H_ * D_ / 2)];
            const float2 v3 = Vb[(size_t)(kq * 4 + 3) * (H_ * D_ / 2)];
            #pragma unroll
            for (int uu = 0; uu < 5; ++uu) {
                const float4 p = *(const float4*)&S[(ug2 * 5 + uu) * 260 + kr2 * 128 + kq * 4];
                accA[uu] += p.x * v0.x + p.y * v1.x + p.z * v2.x + p.w * v3.x;
                accB[uu] += p.x * v0.y + p.y * v1.y + p.z * v2.y + p.w * v3.y;
            }
        }
        if (kr2 == 1) {
            #pragma unroll
            for (int uu = 0; uu < 5; ++uu)
                Ppv[ug2 * 5 + uu][d2] = make_float2(accA[uu], accB[uu]);
        }
        __syncthreads();
        if (kr2 == 0) {
            #pragma unroll
            for (int uu = 0; uu < 5; ++uu) {
                const float2 o = Ppv[ug2 * 5 + uu][d2];
                float* pb = pout + (((size_t)(bh * NCH_ + kc)) * NTOP_ + uh * 20 + ug2 * 5 + uu) * D_ + d2 * 2;
                *(float2*)pb = make_float2(accA[uu] + o.x, accB[uu] + o.y);
            }
        }
    }
}

// ---------------- k4: combine chunk partials, scatter to out -----------------
__global__ __launch_bounds__(128) void k_comb(const float* __restrict__ pmax,
                                              const float* __restrict__ psum,
                                              const float* __restrict__ pout,
                                              const int* __restrict__ topk,
                                              float* __restrict__ out) {
    const int bid = blockIdx.x;          // bh*40 + u
    const int bh  = bid / NTOP_;
    const int u   = bid - bh * NTOP_;
    const int h   = bh & 15, b = bh >> 4;
    const int t   = threadIdx.x;

    float pm[NCH_];
    float M = -INFINITY;
    #pragma unroll
    for (int c = 0; c < NCH_; ++c) {
        pm[c] = pmax[(bh * NCH_ + c) * NTOP_ + u];
        M = fmaxf(M, pm[c]);
    }
    float ssum = 0.0f, o = 0.0f;
    #pragma unroll
    for (int c = 0; c < NCH_; ++c) {
        const float w = __expf(pm[c] - M);
        ssum += psum[(bh * NCH_ + c) * NTOP_ + u] * w;
        o += pout[((size_t)(bh * NCH_ + c) * NTOP_ + u) * D_ + t] * w;
    }
    const int qi = topk[bh * NTOP_ + u];
    out[((size_t)(b * L_ + qi) * H_ + h) * D_ + t] = o / ssum;
}

extern "C" void kernel_launch(void* const* d_in, const int* in_sizes, int n_in,
                              void* d_out, int out_size, void* d_ws, size_t ws_size,
                              hipStream_t stream) {
    const float* Q  = (const float*)d_in[0];
    const float* K  = (const float*)d_in[1];
    const float* V  = (const float*)d_in[2];
    const int* idx  = (const int*)d_in[3];
    float* out      = (float*)d_out;

    char* ws = (char*)d_ws;
    size_t off = 0;
    float* Mws   = (float*)(ws + off); off += (size_t)65536 * 4;
    float* vpart = (float*)(ws + off); off += (size_t)1024 * 128 * 4;
    float* vmean = (float*)(ws + off); off += (size_t)4096 * 4;
    int*   topk  = (int*)(ws + off);   off += 1280 * 4;
    float* pmax  = (float*)(ws + off); off += (size_t)256 * 40 * 4;
    float* psum  = (float*)(ws + off); off += (size_t)256 * 40 * 4;
    float* pout  = (float*)(ws + off); off += (size_t)256 * 40 * 128 * 4;
    unsigned int* Kf = (unsigned int*)(ws + off);
    const size_t kf_bytes = (size_t)32 * L_ * D_ * 2;      // 16.8 MB
    const bool use_f16 = (ws_size >= off + kf_bytes);

    if (use_f16) {
        hipLaunchKernelGGL(kA_pack_vpart, dim3(256 + 1024), dim3(256), 0, stream,
                           K, V, Kf, vpart, 256);
        hipLaunchKernelGGL(k1_sample_f16, dim3(16384), dim3(256), 0, stream,
                           Q, (const uint4*)Kf, idx, Mws);
    } else {
        hipLaunchKernelGGL(kA_pack_vpart, dim3(1024), dim3(256), 0, stream,
                           K, V, Kf, vpart, 0);
        hipLaunchKernelGGL(k1_sample_f32, dim3(16384), dim3(256), 0, stream,
                           Q, K, idx, Mws);
    }
    hipLaunchKernelGGL(k2_rank_refine, dim3(33), dim3(1024), 0, stream,
                       Mws, Q, K, idx, vpart, vmean, topk, use_f16 ? 0.5f : 0.01f);
    hipLaunchKernelGGL(k3_scorepv_fill, dim3(1024), dim3(512), 0, stream,
                       Q, K, V, topk, vmean, pmax, psum, pout, out);
    hipLaunchKernelGGL(k_comb, dim3(1280), dim3(128), 0, stream,
                       pmax, psum, pout, topk, out);
}